// Round 1
// 177.314 us; speedup vs baseline: 1.5730x; 1.5730x over previous
//
#include <hip/hip_runtime.h>

// CTC batch cost (Keras ctc_batch_cost, full lengths).
// B=64, T=2048, C=128 (blank=127), L=256, S=513.
//
// Round-13: FORWARD/BACKWARD SPLIT. R12 counters show we are bound by the
// serial recurrence depth (2047 steps, one wave/block, 69% issue-occupancy
// of one SIMD; HBM 2%, occupancy 0.7%). The product
//   p = f^T [diag(p_{T-1})A] ... [diag(p_1)A] diag(p_0) e01
// is evaluated from both ends at once: wave 0 runs the forward recursion to
// alpha_{1023} (1023 steps), wave 1 runs the transposed recursion
//   c(s') = d(s') + d(s'+1) + skip(s'+2) d(s'+2),  d(s)=c(s)*p_t(z_s)
// from t=2047 down to 1024 (1024 steps); then p = <c_{1024}, alpha_{1023}>.
// Serial depth halves: 2047 -> 1024. Backward is the exact mirror: same 5
// imm-offset LDS gathers/lane, same gates (cross-lane term folds to
// u = d0 + m1f*d1 exported via DPP wave_shl:1), same block-float renorm
// every 4 steps with neighbor adoption in the opposite lane direction
// (frontier moves <=2 states/step downward; adoption seeded by the init
// boundary — same exactness cadence as forward).
// Unchanged from R12: LDS-DMA staging + WAIT_VM(8) never-drain discipline,
// lookahead-4 slots (compile-time j&3), 5 column base pointers, no
// sched_barriers. Two waves per block on different SIMDs of one CU; one
// __syncthreads + 9-FMA lane dot + 64-lane logsumexp combine at the end.

#define B_ 64
#define T_ 2048
#define C_ 128
#define L_ 256
#define BLANK_ (C_ - 1)
#define EPSF 1e-7f
#define LN2F 0.69314718055994530942f
#define CH_ 16                // rows per chunk
#define NCHH_ 64              // chunks per half (T/2/CH)
#define SENT_ (-(1 << 28))    // "lane is all-zero" exponent sentinel

typedef __attribute__((address_space(1))) const void glob_cv;
typedef __attribute__((address_space(3))) void lds_v;

__device__ __forceinline__ void gl2lds16(const float* g, float* l) {
    __builtin_amdgcn_global_load_lds((glob_cv*)g, (lds_v*)l, 16, 0, 0);
}

#define WAIT_VM(n) asm volatile("s_waitcnt vmcnt(" #n ")" ::: "memory")

// lane l -> value of lane l-1; lane 0 -> 0. DPP ctrl 0x138 = wave_shr:1.
__device__ __forceinline__ float dpp_shr1_f(float x) {
    return __int_as_float(
        __builtin_amdgcn_update_dpp(0, __float_as_int(x), 0x138, 0xf, 0xf, false));
}
__device__ __forceinline__ int dpp_shr1_i(int x) {
    return __builtin_amdgcn_update_dpp(0, x, 0x138, 0xf, 0xf, false);
}
// lane l -> value of lane l+1; lane 63 -> 0. DPP ctrl 0x130 = wave_shl:1.
__device__ __forceinline__ float dpp_shl1_f(float x) {
    return __int_as_float(
        __builtin_amdgcn_update_dpp(0, __float_as_int(x), 0x130, 0xf, 0xf, false));
}
__device__ __forceinline__ int dpp_shl1_i(int x) {
    return __builtin_amdgcn_update_dpp(0, x, 0x130, 0xf, 0xf, false);
}

struct G { float pb, p1, p3, p5, p7; };

__launch_bounds__(128, 1)
__global__ void ctc_loss_kernel(const int* __restrict__ y_true,
                                const float* __restrict__ y_pred,
                                float* __restrict__ out) {
    const int b = blockIdx.x;
    const int tid = threadIdx.x;
    const int w = __builtin_amdgcn_readfirstlane(tid >> 6);  // 0=fwd, 1=bwd
    const int l = tid & 63;

    __shared__ float ring[2][4][CH_ * C_];  // 2 waves x 4 bufs x 16x128 = 64 KB

    const int* __restrict__ lab = y_true + b * L_;
    const int4 lv = *(const int4*)(lab + 4 * l);   // labels 4l..4l+3
    const int e1 = lv.x, e3 = lv.y, e5 = lv.z, e7 = lv.w;
    const int em1 = (l > 0) ? lab[4 * l - 1] : -1;
    const float m1f = ((l > 0) && (e1 != em1)) ? 1.0f : 0.0f;  // skip gates
    const float m3f = (e3 != e1) ? 1.0f : 0.0f;
    const float m5f = (e5 != e3) ? 1.0f : 0.0f;
    const float m7f = (e7 != e5) ? 1.0f : 0.0f;
    const float m8f = (l == 63) ? 1.0f : 0.0f;     // state-512 coupling gate

    const float* __restrict__ base = y_pred + (size_t)b * (T_ * C_);

    // Column base pointers into this wave's ring; every gather becomes
    // ds_read vaddr offset:imm (off*4 <= 32256 B, fits the 16-bit imm).
    float* __restrict__ rb = &ring[w][0][0];
    const float* __restrict__ cB = rb + BLANK_;
    const float* __restrict__ c1 = rb + e1;
    const float* __restrict__ c3 = rb + e3;
    const float* __restrict__ c5 = rb + e5;
    const float* __restrict__ c7 = rb + e7;

    auto issue_chunk = [&](int t0, int buf) {
        const float* g = base + (size_t)t0 * C_ + 4 * l;  // lane*16B
        float* d = &ring[w][buf][0];
#pragma unroll
        for (int i = 0; i < 8; ++i)
            gl2lds16(g + i * 256, d + i * 256);
    };

    G g[4];  // lookahead-4 slots; slot index always compile-time (j&3)
    auto fill = [&](int slot, int off) {  // off = buf*2048 + row*128 (const)
        g[slot].pb = cB[off] + EPSF;
        g[slot].p1 = c1[off] + EPSF;
        g[slot].p3 = c3[off] + EPSF;
        g[slot].p5 = c5[off] + EPSF;
        g[slot].p7 = c7[off] + EPSF;
    };

    // linear mantissas at lane-local scale 2^E
    float a0 = 0.f, a1 = 0.f, a2 = 0.f, a3 = 0.f, a4 = 0.f,
          a5 = 0.f, a6 = 0.f, a7 = 0.f, a8 = 0.f;
    int E = SENT_;
    float upscale = 1.0f;  // 2^(E_nbr - E), fixed within a 4-step window

    // ---------------- forward machinery (wave 0) ----------------
    auto step = [&](const G& q) {
        const float up = dpp_shr1_f(a7) * upscale;  // state 8l-1, rescaled
        const float n0 = (a0 + up) * q.pb;
        const float n1 = fmaf(m1f, up, a0 + a1) * q.p1;
        const float n2 = (a1 + a2) * q.pb;
        const float n3 = fmaf(m3f, a1, a2 + a3) * q.p3;
        const float n4 = (a3 + a4) * q.pb;
        const float n5 = fmaf(m5f, a3, a4 + a5) * q.p5;
        const float n6 = (a5 + a6) * q.pb;
        const float n7 = fmaf(m7f, a5, a6 + a7) * q.p7;
        const float n8 = fmaf(m8f, a7, a8) * q.pb;  // state 512
        a0 = n0; a1 = n1; a2 = n2; a3 = n3; a4 = n4;
        a5 = n5; a6 = n6; a7 = n7; a8 = n8;
    };

    auto boundary = [&]() {
        float mx = fmaxf(fmaxf(fmaxf(a0, a1), fmaxf(a2, a3)),
                         fmaxf(fmaxf(a4, a5), fmaxf(a6, a7)));
        mx = fmaxf(mx, a8);
        const bool z = (mx == 0.0f);
        const int e = (int)(__float_as_uint(mx) >> 23) - 127;
        const float s = z ? 1.0f : __uint_as_float((unsigned)(127 - e) << 23);
        a0 *= s; a1 *= s; a2 *= s; a3 *= s; a4 *= s;
        a5 *= s; a6 *= s; a7 *= s; a8 *= s;
        E = z ? SENT_ : (E + e);
        int upE = dpp_shr1_i(E);
        if (l == 0) upE = SENT_;
        if (E == SENT_) E = upE;            // adopt neighbor scale (exact)
        int d = upE - E;
        d = min(max(d, -126), 120);
        upscale = __uint_as_float((unsigned)(d + 127) << 23);
    };

    auto run_chunk = [&](int bc, int bn, int jstart, bool last) {
#pragma unroll
        for (int j = 0; j < CH_; ++j) {
            if (j == 0 && jstart) continue;      // folds at compile time
            step(g[j & 3]);
            if (!last || j < 12) {
                const int off = (j < 12) ? (bc * 2048 + (j + 4) * 128)
                                         : (bn * 2048 + (j - 12) * 128);
                fill(j & 3, off);
            }
            if ((j & 3) == 3) boundary();
        }
    };

    // ---------------- backward machinery (wave 1) ----------------
    // b-values are c_t mantissas; step consumes row t (decreasing).
    auto stepb = [&](const G& q) {
        const float d0 = a0 * q.pb, d1 = a1 * q.p1, d2 = a2 * q.pb,
                    d3 = a3 * q.p3, d4 = a4 * q.pb, d5 = a5 * q.p5,
                    d6 = a6 * q.pb, d7 = a7 * q.p7, d8 = a8 * q.pb;
        const float u = fmaf(m1f, d1, d0);          // exported to lane l-1
        const float dn = dpp_shl1_f(u) * upscale;   // lane l+1's u, rescaled
        a0 = d0 + d1;
        a1 = fmaf(m3f, d3, d1 + d2);
        a2 = d2 + d3;
        a3 = fmaf(m5f, d5, d3 + d4);
        a4 = d4 + d5;
        a5 = fmaf(m7f, d7, d5 + d6);
        a6 = d6 + d7;
        a7 = fmaf(m8f, d8, d7 + dn);                // state 511 (+512 on l=63)
        a8 = d8;                                    // state 512
    };

    auto boundaryb = [&]() {
        float mx = fmaxf(fmaxf(fmaxf(a0, a1), fmaxf(a2, a3)),
                         fmaxf(fmaxf(a4, a5), fmaxf(a6, a7)));
        mx = fmaxf(mx, a8);
        const bool z = (mx == 0.0f);
        const int e = (int)(__float_as_uint(mx) >> 23) - 127;
        const float s = z ? 1.0f : __uint_as_float((unsigned)(127 - e) << 23);
        a0 *= s; a1 *= s; a2 *= s; a3 *= s; a4 *= s;
        a5 *= s; a6 *= s; a7 *= s; a8 *= s;
        E = z ? SENT_ : (E + e);
        int upE = dpp_shl1_i(E);            // neighbor is lane l+1
        if (l == 63) upE = SENT_;
        if (E == SENT_) E = upE;
        int d = upE - E;
        d = min(max(d, -126), 120);
        upscale = __uint_as_float((unsigned)(d + 127) << 23);
    };

    // step j consumes row 15-j (slot j&3); refill with row 15-(j+4).
    auto run_chunkb = [&](int bc, int bn, bool last) {
#pragma unroll
        for (int j = 0; j < CH_; ++j) {
            stepb(g[j & 3]);
            if (!last || j < 12) {
                const int off = (j < 12) ? (bc * 2048 + (11 - j) * 128)
                                         : (bn * 2048 + (27 - j) * 128);
                fill(j & 3, off);
            }
            if ((j & 3) == 3) boundaryb();
        }
    };

    if (w == 0) {
        // ======== forward: chunks 0..63 (t = 0..1023) ========
        issue_chunk(0, 0);
        issue_chunk(CH_, 1);
        issue_chunk(2 * CH_, 2);

        WAIT_VM(8);                        // chunks 0,1 landed; 2 in flight
        issue_chunk(3 * CH_, 3);
        if (l == 0) { a0 = rb[BLANK_] + EPSF; a1 = rb[e1] + EPSF; E = 0; }
        boundary();                        // seeds lane1's adoption of E
        fill(1, 1 * 128);                  // rows 1..4 for slots 1,2,3,0
        fill(2, 2 * 128);
        fill(3, 3 * 128);
        fill(0, 4 * 128);
        run_chunk(0, 1, 1, false);
        WAIT_VM(8); issue_chunk(4 * CH_, 0); run_chunk(1, 2, 0, false);
        WAIT_VM(8); issue_chunk(5 * CH_, 1); run_chunk(2, 3, 0, false);
        WAIT_VM(8); issue_chunk(6 * CH_, 2); run_chunk(3, 0, 0, false);

        for (int m = 1; m <= 14; ++m) {    // chunks 4..59
            const int c = 4 * m;
            WAIT_VM(8); issue_chunk((c + 3) * CH_, 3); run_chunk(0, 1, 0, false);
            WAIT_VM(8); issue_chunk((c + 4) * CH_, 0); run_chunk(1, 2, 0, false);
            WAIT_VM(8); issue_chunk((c + 5) * CH_, 1); run_chunk(2, 3, 0, false);
            WAIT_VM(8); issue_chunk((c + 6) * CH_, 2); run_chunk(3, 0, 0, false);
        }

        WAIT_VM(8); issue_chunk(63 * CH_, 3); run_chunk(0, 1, 0, false);
        WAIT_VM(8);                        // 62 landed; 63 in flight
        run_chunk(1, 2, 0, false);
        WAIT_VM(0);                        // 63 landed
        run_chunk(2, 3, 0, false);
        run_chunk(3, 3, 0, true);
        // a0..a8, E now hold alpha_{1023}
    } else {
        // ======== backward: chunks 127..64 (t = 2047..1024), order q ========
        auto issq = [&](int q, int buf) { issue_chunk((127 - q) * CH_, buf); };
        issq(0, 0); issq(1, 1); issq(2, 2);

        WAIT_VM(8);
        issq(3, 3);
        if (l == 63) { a7 = 1.0f; a8 = 1.0f; E = 0; }  // c_2048 = f
        boundaryb();                       // seeds lane62's adoption of E
        fill(0, 15 * 128);                 // rows 15,14,13,12 -> slots 0..3
        fill(1, 14 * 128);
        fill(2, 13 * 128);
        fill(3, 12 * 128);
        run_chunkb(0, 1, false);
        WAIT_VM(8); issq(4, 0); run_chunkb(1, 2, false);
        WAIT_VM(8); issq(5, 1); run_chunkb(2, 3, false);
        WAIT_VM(8); issq(6, 2); run_chunkb(3, 0, false);

        for (int m = 1; m <= 14; ++m) {
            const int c = 4 * m;
            WAIT_VM(8); issq(c + 3, 3); run_chunkb(0, 1, false);
            WAIT_VM(8); issq(c + 4, 0); run_chunkb(1, 2, false);
            WAIT_VM(8); issq(c + 5, 1); run_chunkb(2, 3, false);
            WAIT_VM(8); issq(c + 6, 2); run_chunkb(3, 0, false);
        }

        WAIT_VM(8); issq(63, 3); run_chunkb(0, 1, false);
        WAIT_VM(8);
        run_chunkb(1, 2, false);
        WAIT_VM(0);
        run_chunkb(2, 3, false);
        run_chunkb(3, 3, true);
        // a0..a8, E now hold c_{1024}; export to LDS (own ring, drained)
        float* xf = &ring[1][0][0];
        xf[0 * 64 + l] = a0; xf[1 * 64 + l] = a1; xf[2 * 64 + l] = a2;
        xf[3 * 64 + l] = a3; xf[4 * 64 + l] = a4; xf[5 * 64 + l] = a5;
        xf[6 * 64 + l] = a6; xf[7 * 64 + l] = a7; xf[8 * 64 + l] = a8;
        ((int*)xf)[9 * 64 + l] = E;
    }

    __syncthreads();

    if (w == 0) {
        // p = sum_s alpha_{1023}(s) * c_{1024}(s); lane-local dot then
        // 64-lane logsumexp over block-float partials.
        const float* xf = &ring[1][0][0];
        float sd = a0 * xf[0 * 64 + l];
        sd = fmaf(a1, xf[1 * 64 + l], sd);
        sd = fmaf(a2, xf[2 * 64 + l], sd);
        sd = fmaf(a3, xf[3 * 64 + l], sd);
        sd = fmaf(a4, xf[4 * 64 + l], sd);
        sd = fmaf(a5, xf[5 * 64 + l], sd);
        sd = fmaf(a6, xf[6 * 64 + l], sd);
        sd = fmaf(a7, xf[7 * 64 + l], sd);
        sd = fmaf(a8, xf[8 * 64 + l], sd);
        const int E2 = ((const int*)xf)[9 * 64 + l];
        const bool nz = (sd > 0.0f);
        int Es = nz ? (E + E2) : SENT_;
        int M = Es;
#pragma unroll
        for (int o = 32; o; o >>= 1) M = max(M, __shfl_xor(M, o));
        int d = Es - M;
        d = max(d, -126);
        float val = nz ? sd * __uint_as_float((unsigned)(d + 127) << 23) : 0.0f;
#pragma unroll
        for (int o = 32; o; o >>= 1) val += __shfl_xor(val, o);
        if (l == 0) out[b] = -(__logf(val) + (float)M * LN2F);
    }
}

extern "C" void kernel_launch(void* const* d_in, const int* in_sizes, int n_in,
                              void* d_out, int out_size, void* d_ws, size_t ws_size,
                              hipStream_t stream) {
    const int* y_true = (const int*)d_in[0];
    const float* y_pred = (const float*)d_in[1];
    float* out = (float*)d_out;
    ctc_loss_kernel<<<B_, 128, 0, stream>>>(y_true, y_pred, out);
}